// Round 1
// baseline (724.077 us; speedup 1.0000x reference)
//
#include <hip/hip_runtime.h>
#include <cstdint>
#include <cstddef>

// ---------------------------------------------------------------------------
// DotProductAttention: out = softmax_causal((x@Q/32) @ (x@K)^T) @ (x@V)
//   B=4, S=4096, D=1024, fp32 in/out, bf16 MFMA compute (threshold allows).
// Pipeline (all on `stream`):
//   1. cvt:        x fp32 -> x_bf16
//   2. transpose:  Q,K,V fp32 [k][n] -> Wt bf16 [n][k]   (Bt layout for GEMM)
//   3. gemm_bt x3: Qx = x@Q * 1/32, Kx = x@K, Vtmp = x@V      (bf16 out)
//   4. transpose:  Vtmp [s][d] -> Vxt [d][s]             (Bt layout for PV)
//   5. gemm_bt:    S = Qx @ Kx^T  (causal block skip, bf16 out)
//   6. softmax:    row-wise, in-place S->P, zero-pad rows to 128 boundary
//   7. gemm_bt:    out = P @ Vxt^T (causal k-limit, fp32 out)
// Workspace map (needs 224 MB):
//   [0,32M)    Qx bf16          [32M,64M)  Kx bf16      [64M,96M) Vxt bf16
//   [96M,224M) S/P bf16 [B][S][S]  -- early phase reuse:
//       x_bf16 @96M (32M), Qt@128M Kt@130M Vt@132M (2M each), Vtmp@136M (32M)
// ---------------------------------------------------------------------------

typedef unsigned short u16;
typedef __bf16  bf16x8 __attribute__((ext_vector_type(8)));
typedef float   f32x4  __attribute__((ext_vector_type(4)));
typedef unsigned short u16x4 __attribute__((ext_vector_type(4)));

typedef __attribute__((address_space(1))) void gvoid;
typedef __attribute__((address_space(3))) void lvoid;

__device__ __forceinline__ u16 f2bf(float f) {
  union { float f; unsigned u; } v; v.f = f;
  unsigned u = v.u;
  u += 0x7FFFu + ((u >> 16) & 1u);   // round-to-nearest-even
  return (u16)(u >> 16);
}
__device__ __forceinline__ float bf2f(u16 h) {
  union { unsigned u; float f; } v; v.u = ((unsigned)h) << 16;
  return v.f;
}
// async global->LDS DMA, 16B per lane; LDS dest = wave-uniform base + lane*16
__device__ __forceinline__ void async16(const void* g, void* l) {
  __builtin_amdgcn_global_load_lds((gvoid*)(void*)g, (lvoid*)l, 16, 0, 0);
}

// --------------------------- elementwise convert ---------------------------
__global__ void __launch_bounds__(256) cvt_f32_bf16(const float4* __restrict__ in,
                                                    u16* __restrict__ out, int n4) {
  int i = blockIdx.x * 256 + threadIdx.x;
  if (i >= n4) return;
  float4 v = in[i];
  u16x4 o = { f2bf(v.x), f2bf(v.y), f2bf(v.z), f2bf(v.w) };
  *(u16x4*)(out + 4 * (size_t)i) = o;
}

// ------------------------------- transpose ---------------------------------
__device__ __forceinline__ u16 to_bf(float v) { return f2bf(v); }
__device__ __forceinline__ u16 to_bf(u16 v)   { return v; }

template <typename TIN>
__global__ void __launch_bounds__(256) transpose_to_bf16(
    const TIN* __restrict__ in, u16* __restrict__ out,
    int rows, int cols, long inStride, long outStride) {
  __shared__ u16 t[64][68];                 // 68: stride 136B -> 2-way bank alias (free)
  int rt = blockIdx.x * 64, ct = blockIdx.y * 64;
  long ib = (long)blockIdx.z * inStride, ob = (long)blockIdx.z * outStride;
  int tx = threadIdx.x & 63, ty = threadIdx.x >> 6;
#pragma unroll
  for (int r = ty; r < 64; r += 4)
    t[r][tx] = to_bf(in[ib + (long)(rt + r) * cols + ct + tx]);
  __syncthreads();
#pragma unroll
  for (int r = ty; r < 64; r += 4)
    out[ob + (long)(ct + r) * rows + rt + tx] = t[tx][r];
}

// ------------------------------- GEMM core ---------------------------------
// C[m][n] = alpha * sum_k A[m][k] * Bt[n][k]; A,Bt bf16 row-major.
// 128x128 tile, BK=32, 256 threads = 4 waves (2x2), 4x4 16x16x32 MFMAs/wave.
// CSKIP: skip blocks with ntile > mtile (causal upper triangle).
// CK:    limit k-reduction to (mtile+1)*128 (causal PV).
template <bool OUTF32, bool CSKIP, bool CK>
__global__ void __launch_bounds__(256) gemm_bt(
    const u16* __restrict__ A, const u16* __restrict__ Bt, void* __restrict__ C,
    int K, int lda, int ldb, int ldc,
    long aStride, long bStride, long cStride, float alpha) {
  const int mt = blockIdx.x, nt = blockIdx.y, bz = blockIdx.z;
  if (CSKIP && nt > mt) return;
  const int tid = threadIdx.x, wv = tid >> 6, ln = tid & 63;
  const u16* Ag = A + (long)bz * aStride + (long)(mt * 128) * lda;
  const u16* Bg = Bt + (long)bz * bStride + (long)(nt * 128) * ldb;

  __shared__ __align__(16) __bf16 As[128 * 32];
  __shared__ __align__(16) __bf16 Bs[128 * 32];

  f32x4 acc[4][4];
#pragma unroll
  for (int i = 0; i < 4; ++i)
#pragma unroll
    for (int j = 0; j < 4; ++j)
#pragma unroll
      for (int r = 0; r < 4; ++r) acc[i][j][r] = 0.f;

  const int kend = CK ? (((mt + 1) * 128 < K) ? (mt + 1) * 128 : K) : K;
  const int mrow = (wv & 1) * 64, nrow = (wv >> 1) * 64;
  const int lr = ln & 15, quad = ln >> 4;

  for (int k0 = 0; k0 < kend; k0 += 32) {
#pragma unroll
    for (int r = 0; r < 2; ++r) {
      int chunk = (wv + 4 * r) * 64 + ln;          // 0..511
      int row = chunk >> 2, c8 = (chunk & 3) << 3; // row 0..127, col8 0/8/16/24
      async16(Ag + (long)row * lda + k0 + c8, &As[(wv + 4 * r) * 512]);
      async16(Bg + (long)row * ldb + k0 + c8, &Bs[(wv + 4 * r) * 512]);
    }
    __syncthreads();   // drains vmcnt before barrier
    bf16x8 af[4], bf[4];
#pragma unroll
    for (int i = 0; i < 4; ++i)
      af[i] = *(const bf16x8*)&As[(mrow + i * 16 + lr) * 32 + quad * 8];
#pragma unroll
    for (int j = 0; j < 4; ++j)
      bf[j] = *(const bf16x8*)&Bs[(nrow + j * 16 + lr) * 32 + quad * 8];
#pragma unroll
    for (int i = 0; i < 4; ++i)
#pragma unroll
      for (int j = 0; j < 4; ++j)
        acc[i][j] = __builtin_amdgcn_mfma_f32_16x16x32_bf16(af[i], bf[j], acc[i][j], 0, 0, 0);
    __syncthreads();   // protect LDS from next stage
  }

  // epilogue: C/D layout col=lane&15, row=(lane>>4)*4+reg  [verified m89/m91]
  const long cb = (long)bz * cStride;
#pragma unroll
  for (int i = 0; i < 4; ++i) {
    int row0 = mt * 128 + mrow + i * 16 + quad * 4;
#pragma unroll
    for (int j = 0; j < 4; ++j) {
      int col = nt * 128 + nrow + j * 16 + lr;
#pragma unroll
      for (int r = 0; r < 4; ++r) {
        float v = acc[i][j][r] * alpha;
        long idx = cb + (long)(row0 + r) * ldc + col;
        if (OUTF32) ((float*)C)[idx] = v;
        else        ((u16*)C)[idx]  = f2bf(v);
      }
    }
  }
}

// ------------------------------ row softmax --------------------------------
// One block per (row, batch). Row length L=row+1 (causal). Registers hold the
// row (<=16 floats/thread). Also zero-pads [L, ceil128(L)) so PV reads no 0xAA.
__global__ void __launch_bounds__(256) softmax_rows(u16* __restrict__ Sb,
                                                    long bStride, int S) {
  const int row = blockIdx.x;
  u16* p = Sb + (long)blockIdx.y * bStride + (long)row * S;
  const int L = row + 1;
  const int Lpad = (L + 127) & ~127;
  const int tid = threadIdx.x, ln = tid & 63, wv = tid >> 6;
  __shared__ float red[8];

  float vals[16];
  float lmax = -3.4e38f;
#pragma unroll
  for (int k = 0; k < 16; ++k) {
    int j = tid + k * 256;
    if (j < L) { float v = bf2f(p[j]); vals[k] = v; lmax = fmaxf(lmax, v); }
  }
#pragma unroll
  for (int o = 32; o > 0; o >>= 1) lmax = fmaxf(lmax, __shfl_down(lmax, o));
  if (ln == 0) red[wv] = lmax;
  __syncthreads();
  float m = fmaxf(fmaxf(red[0], red[1]), fmaxf(red[2], red[3]));

  float lsum = 0.f;
#pragma unroll
  for (int k = 0; k < 16; ++k) {
    int j = tid + k * 256;
    if (j < L) { float e = __expf(vals[k] - m); vals[k] = e; lsum += e; }
  }
#pragma unroll
  for (int o = 32; o > 0; o >>= 1) lsum += __shfl_down(lsum, o);
  __syncthreads();                    // red[0..3] reads (m) done before reuse
  if (ln == 0) red[wv] = lsum;
  __syncthreads();
  float inv = 1.f / (red[0] + red[1] + red[2] + red[3]);
#pragma unroll
  for (int k = 0; k < 16; ++k) {
    int j = tid + k * 256;
    if (j < L) p[j] = f2bf(vals[k] * inv);
  }
  for (int j = L + tid; j < Lpad; j += 256) p[j] = 0;
}

// ------------------------------- launcher ----------------------------------
extern "C" void kernel_launch(void* const* d_in, const int* in_sizes, int n_in,
                              void* d_out, int out_size, void* d_ws, size_t ws_size,
                              hipStream_t stream) {
  const float* x = (const float*)d_in[0];
  const float* Q = (const float*)d_in[1];
  const float* K = (const float*)d_in[2];
  const float* V = (const float*)d_in[3];
  float* out = (float*)d_out;

  constexpr int  Bb = 4, S = 4096, D = 1024;
  constexpr long MB = 1024 * 1024;
  if (ws_size < (size_t)(224 * MB)) return;   // insufficient workspace -> loud absmax fail

  char* ws = (char*)d_ws;
  u16* Qx   = (u16*)(ws);             // [B][S][D]
  u16* Kx   = (u16*)(ws + 32 * MB);   // [B][S][D]
  u16* Vxt  = (u16*)(ws + 64 * MB);   // [B][D][S]
  u16* Sb   = (u16*)(ws + 96 * MB);   // [B][S][S]
  u16* XB   = (u16*)(ws + 96 * MB);   // x bf16 (dead before Sb written)
  u16* Qt   = (u16*)(ws + 128 * MB);  // Q^T bf16 [n][k]
  u16* Kt   = (u16*)(ws + 130 * MB);
  u16* Vt   = (u16*)(ws + 132 * MB);
  u16* Vtmp = (u16*)(ws + 136 * MB);  // x@V before transpose

  const long SD = (long)S * D, SS = (long)S * S;

  // 1. x -> bf16
  cvt_f32_bf16<<<dim3((Bb * S * D / 4) / 256), 256, 0, stream>>>(
      (const float4*)x, XB, Bb * S * D / 4);

  // 2. weight transposes (fp32 [k][n] -> bf16 [n][k])
  transpose_to_bf16<float><<<dim3(16, 16, 1), 256, 0, stream>>>(Q, Qt, 1024, 1024, 0, 0);
  transpose_to_bf16<float><<<dim3(16, 16, 1), 256, 0, stream>>>(K, Kt, 1024, 1024, 0, 0);
  transpose_to_bf16<float><<<dim3(16, 16, 1), 256, 0, stream>>>(V, Vt, 1024, 1024, 0, 0);

  // 3. projections (1/sqrt(1024) folded into Q)
  gemm_bt<false, false, false><<<dim3(128, 8, 1), 256, 0, stream>>>(
      XB, Qt, Qx, 1024, 1024, 1024, 1024, 0, 0, 0, 0.03125f);
  gemm_bt<false, false, false><<<dim3(128, 8, 1), 256, 0, stream>>>(
      XB, Kt, Kx, 1024, 1024, 1024, 1024, 0, 0, 0, 1.0f);
  gemm_bt<false, false, false><<<dim3(128, 8, 1), 256, 0, stream>>>(
      XB, Vt, Vtmp, 1024, 1024, 1024, 1024, 0, 0, 0, 1.0f);

  // 4. Vtmp [b][s][d] -> Vxt [b][d][s]
  transpose_to_bf16<u16><<<dim3(64, 16, Bb), 256, 0, stream>>>(
      Vtmp, Vxt, S, D, SD, SD);

  // 5. causal scores: S = Qx @ Kx^T (block-skip upper triangle)
  gemm_bt<false, true, false><<<dim3(32, 32, Bb), 256, 0, stream>>>(
      Qx, Kx, Sb, 1024, 1024, 1024, S, SD, SD, SS, 1.0f);

  // 6. row softmax in place
  softmax_rows<<<dim3(S, Bb), 256, 0, stream>>>(Sb, SS, S);

  // 7. out = P @ Vxt^T (causal k-limit per row-block)
  gemm_bt<true, false, true><<<dim3(32, 8, Bb), 256, 0, stream>>>(
      Sb, Vxt, out, S, S, S, D, SS, SD, SD, 1.0f);
}

// Round 3
// 588.834 us; speedup vs baseline: 1.2297x; 1.2297x over previous
//
#include <hip/hip_runtime.h>
#include <cstdint>
#include <cstddef>
#include <cmath>

// ---------------------------------------------------------------------------
// DotProductAttention: out = softmax_causal((x@Q/32) @ (x@K)^T) @ (x@V)
//   B=4, S=4096, D=1024, fp32 in/out, bf16 MFMA compute.
// R3 = R2 with the batch-stride bug fixed: QKx is [B*S][2048] interleaved, so
// the scores GEMM batch stride is S*2048 = 2*SD (R2 passed SD -> batches 1..3
// read wrong rows, absmax 2.84).
// Structure:
//   - BK=64 GEMM K-loop as two BK=32 panels (half the barrier-drain events)
//   - fused Q+K projection (N=2048, interleaved [row][2048] output)
//   - triangular-compacted grid for causal scores (528 blocks/batch)
//   - PV launches longest (largest-mt) blocks first for tail balance
// Workspace map (224 MB):
//   [0,64)   QKx bf16 [B*S][2048]  (Qx=+0, Kx=+1024, ld 2048)
//   [64,96)  Vxt bf16 [B][D][S]
//   [96,224) Sb bf16 [B][S][S]  -- early-phase reuse (all dead before Sb):
//       Vtmp@96 (32M), XB@128 (32M), WTqk@160 (4M), WTv@164 (2M)
// ---------------------------------------------------------------------------

typedef unsigned short u16;
typedef __bf16  bf16x8 __attribute__((ext_vector_type(8)));
typedef float   f32x4  __attribute__((ext_vector_type(4)));
typedef unsigned short u16x4 __attribute__((ext_vector_type(4)));

typedef __attribute__((address_space(1))) void gvoid;
typedef __attribute__((address_space(3))) void lvoid;

__device__ __forceinline__ u16 f2bf(float f) {
  union { float f; unsigned u; } v; v.f = f;
  unsigned u = v.u;
  u += 0x7FFFu + ((u >> 16) & 1u);   // round-to-nearest-even
  return (u16)(u >> 16);
}
__device__ __forceinline__ float bf2f(u16 h) {
  union { unsigned u; float f; } v; v.u = ((unsigned)h) << 16;
  return v.f;
}
__device__ __forceinline__ void async16(const void* g, void* l) {
  __builtin_amdgcn_global_load_lds((gvoid*)(void*)g, (lvoid*)l, 16, 0, 0);
}

// --------------------------- elementwise convert ---------------------------
__global__ void __launch_bounds__(256) cvt_f32_bf16(const float4* __restrict__ in,
                                                    u16* __restrict__ out, int n4) {
  int i = blockIdx.x * 256 + threadIdx.x;
  if (i >= n4) return;
  float4 v = in[i];
  u16x4 o = { f2bf(v.x), f2bf(v.y), f2bf(v.z), f2bf(v.w) };
  *(u16x4*)(out + 4 * (size_t)i) = o;
}

// ------------------------------- transpose ---------------------------------
__device__ __forceinline__ u16 to_bfs(float v, float s) { return f2bf(v * s); }
__device__ __forceinline__ u16 to_bfs(u16 v, float)     { return v; }

template <typename TIN>
__global__ void __launch_bounds__(256) transpose_to_bf16(
    const TIN* __restrict__ in, u16* __restrict__ out,
    int rows, int cols, long inStride, long outStride, float scale) {
  __shared__ u16 t[64][68];                 // stride 136B -> 2-way alias (free)
  int rt = blockIdx.x * 64, ct = blockIdx.y * 64;
  long ib = (long)blockIdx.z * inStride, ob = (long)blockIdx.z * outStride;
  int tx = threadIdx.x & 63, ty = threadIdx.x >> 6;
#pragma unroll
  for (int r = ty; r < 64; r += 4)
    t[r][tx] = to_bfs(in[ib + (long)(rt + r) * cols + ct + tx], scale);
  __syncthreads();
#pragma unroll
  for (int r = ty; r < 64; r += 4)
    out[ob + (long)(ct + r) * rows + rt + tx] = t[tx][r];
}

// ------------------------------- GEMM core ---------------------------------
// C[m][n] = alpha * sum_k A[m][k] * Bt[n][k]; A,Bt bf16 row-major.
// 128x128 tile, BK=64 (two BK=32 LDS panels), 256 threads = 4 waves (2x2),
// 4x4 16x16x32 MFMAs/wave per panel.
// TRI: blockIdx.x is a compacted lower-triangular index (causal scores).
// CK:  limit k-reduction to (mt+1)*128 (causal PV); mt reversed for balance.
template <bool OUTF32, bool TRI, bool CK>
__global__ void __launch_bounds__(256) gemm_bt(
    const u16* __restrict__ A, const u16* __restrict__ Bt, void* __restrict__ C,
    int K, int lda, int ldb, int ldc,
    long aStride, long bStride, long cStride, float alpha) {
  int mt, nt;
  if (TRI) {
    const int bid = blockIdx.x;
    int m = (int)((sqrtf(8.0f * (float)bid + 1.0f) - 1.0f) * 0.5f);
    while ((m + 1) * (m + 2) / 2 <= bid) ++m;
    while (m * (m + 1) / 2 > bid) --m;
    mt = m; nt = bid - m * (m + 1) / 2;
  } else {
    mt = CK ? (int)(gridDim.x - 1 - blockIdx.x) : (int)blockIdx.x;
    nt = blockIdx.y;
  }
  const int bz = blockIdx.z;
  const int tid = threadIdx.x, wv = tid >> 6, ln = tid & 63;
  const u16* Ag = A + (long)bz * aStride + (long)(mt * 128) * lda;
  const u16* Bg = Bt + (long)bz * bStride + (long)(nt * 128) * ldb;

  __shared__ __align__(16) __bf16 As[2][128 * 32];
  __shared__ __align__(16) __bf16 Bs[2][128 * 32];

  f32x4 acc[4][4];
#pragma unroll
  for (int i = 0; i < 4; ++i)
#pragma unroll
    for (int j = 0; j < 4; ++j)
#pragma unroll
      for (int r = 0; r < 4; ++r) acc[i][j][r] = 0.f;

  const int kend = CK ? (((mt + 1) * 128 < K) ? (mt + 1) * 128 : K) : K;
  const int mrow = (wv & 1) * 64, nrow = (wv >> 1) * 64;
  const int lr = ln & 15, quad = ln >> 4;

  for (int k0 = 0; k0 < kend; k0 += 64) {
#pragma unroll
    for (int p = 0; p < 2; ++p)
#pragma unroll
      for (int r = 0; r < 2; ++r) {
        int chunk = (wv + 4 * r) * 64 + ln;          // 0..511
        int row = chunk >> 2, c8 = (chunk & 3) << 3; // row 0..127, col8 0..24
        async16(Ag + (long)row * lda + k0 + p * 32 + c8, &As[p][(wv + 4 * r) * 512]);
        async16(Bg + (long)row * ldb + k0 + p * 32 + c8, &Bs[p][(wv + 4 * r) * 512]);
      }
    __syncthreads();   // drains vmcnt before barrier
#pragma unroll
    for (int p = 0; p < 2; ++p) {
      bf16x8 af[4], bfr[4];
#pragma unroll
      for (int i = 0; i < 4; ++i)
        af[i] = *(const bf16x8*)&As[p][(mrow + i * 16 + lr) * 32 + quad * 8];
#pragma unroll
      for (int j = 0; j < 4; ++j)
        bfr[j] = *(const bf16x8*)&Bs[p][(nrow + j * 16 + lr) * 32 + quad * 8];
#pragma unroll
      for (int i = 0; i < 4; ++i)
#pragma unroll
        for (int j = 0; j < 4; ++j)
          acc[i][j] = __builtin_amdgcn_mfma_f32_16x16x32_bf16(af[i], bfr[j], acc[i][j], 0, 0, 0);
    }
    __syncthreads();   // protect LDS from next stage
  }

  // epilogue: C/D layout col=lane&15, row=(lane>>4)*4+reg  [verified m89/m91]
  const long cb = (long)bz * cStride;
#pragma unroll
  for (int i = 0; i < 4; ++i) {
    int row0 = mt * 128 + mrow + i * 16 + quad * 4;
#pragma unroll
    for (int j = 0; j < 4; ++j) {
      int col = nt * 128 + nrow + j * 16 + lr;
#pragma unroll
      for (int r = 0; r < 4; ++r) {
        float v = acc[i][j][r] * alpha;
        long idx = cb + (long)(row0 + r) * ldc + col;
        if (OUTF32) ((float*)C)[idx] = v;
        else        ((u16*)C)[idx]  = f2bf(v);
      }
    }
  }
}

// ------------------------------ row softmax --------------------------------
__global__ void __launch_bounds__(256) softmax_rows(u16* __restrict__ Sb,
                                                    long bStride, int S) {
  const int row = blockIdx.x;
  u16* p = Sb + (long)blockIdx.y * bStride + (long)row * S;
  const int L = row + 1;
  const int Lpad = (L + 127) & ~127;
  const int tid = threadIdx.x, ln = tid & 63, wv = tid >> 6;
  __shared__ float red[8];

  float vals[16];
  float lmax = -3.4e38f;
#pragma unroll
  for (int k = 0; k < 16; ++k) {
    int j = tid + k * 256;
    if (j < L) { float v = bf2f(p[j]); vals[k] = v; lmax = fmaxf(lmax, v); }
  }
#pragma unroll
  for (int o = 32; o > 0; o >>= 1) lmax = fmaxf(lmax, __shfl_down(lmax, o));
  if (ln == 0) red[wv] = lmax;
  __syncthreads();
  float m = fmaxf(fmaxf(red[0], red[1]), fmaxf(red[2], red[3]));

  float lsum = 0.f;
#pragma unroll
  for (int k = 0; k < 16; ++k) {
    int j = tid + k * 256;
    if (j < L) { float e = __expf(vals[k] - m); vals[k] = e; lsum += e; }
  }
#pragma unroll
  for (int o = 32; o > 0; o >>= 1) lsum += __shfl_down(lsum, o);
  __syncthreads();
  if (ln == 0) red[wv] = lsum;
  __syncthreads();
  float inv = 1.f / (red[0] + red[1] + red[2] + red[3]);
#pragma unroll
  for (int k = 0; k < 16; ++k) {
    int j = tid + k * 256;
    if (j < L) p[j] = f2bf(vals[k] * inv);
  }
  for (int j = L + tid; j < Lpad; j += 256) p[j] = 0;
}

// ------------------------------- launcher ----------------------------------
extern "C" void kernel_launch(void* const* d_in, const int* in_sizes, int n_in,
                              void* d_out, int out_size, void* d_ws, size_t ws_size,
                              hipStream_t stream) {
  const float* x = (const float*)d_in[0];
  const float* Q = (const float*)d_in[1];
  const float* K = (const float*)d_in[2];
  const float* V = (const float*)d_in[3];
  float* out = (float*)d_out;

  constexpr int  Bb = 4, S = 4096, D = 1024;
  constexpr long MB = 1024 * 1024;
  if (ws_size < (size_t)(224 * MB)) return;

  char* ws = (char*)d_ws;
  u16* QKx  = (u16*)(ws);             // [B*S][2048]  Qx=+0, Kx=+1024
  u16* Vxt  = (u16*)(ws + 64 * MB);   // [B][D][S]
  u16* Sb   = (u16*)(ws + 96 * MB);   // [B][S][S]
  u16* Vtmp = (u16*)(ws + 96 * MB);   // [B][S][D]   (dead before Sb written)
  u16* XB   = (u16*)(ws + 128 * MB);  // x bf16      (dead before Sb written)
  u16* WTqk = (u16*)(ws + 160 * MB);  // [2048][1024] (Qt rows 0..1023, Kt 1024..2047)
  u16* WTv  = (u16*)(ws + 164 * MB);  // [1024][1024]

  const long SD = (long)S * D, SS = (long)S * S;

  // 1. x -> bf16
  cvt_f32_bf16<<<dim3((Bb * S * D / 4) / 256), 256, 0, stream>>>(
      (const float4*)x, XB, Bb * S * D / 4);

  // 2. weight transposes (fp32 [k][n] -> bf16 [n][k]); 1/32 folded into Qt
  transpose_to_bf16<float><<<dim3(16, 16, 1), 256, 0, stream>>>(
      Q, WTqk, 1024, 1024, 0, 0, 0.03125f);
  transpose_to_bf16<float><<<dim3(16, 16, 1), 256, 0, stream>>>(
      K, WTqk + 1024 * 1024, 1024, 1024, 0, 0, 1.0f);
  transpose_to_bf16<float><<<dim3(16, 16, 1), 256, 0, stream>>>(
      V, WTv, 1024, 1024, 0, 0, 1.0f);

  // 3a. fused Q,K projection -> QKx [B*S][2048]
  gemm_bt<false, false, false><<<dim3(128, 16, 1), 256, 0, stream>>>(
      XB, WTqk, QKx, 1024, 1024, 1024, 2048, 0, 0, 0, 1.0f);
  // 3b. V projection -> Vtmp
  gemm_bt<false, false, false><<<dim3(128, 8, 1), 256, 0, stream>>>(
      XB, WTv, Vtmp, 1024, 1024, 1024, 1024, 0, 0, 0, 1.0f);

  // 4. Vtmp [b][s][d] -> Vxt [b][d][s]
  transpose_to_bf16<u16><<<dim3(64, 16, Bb), 256, 0, stream>>>(
      Vtmp, Vxt, S, D, SD, SD, 1.0f);

  // 5. causal scores: Sb = Qx @ Kx^T, compacted triangular grid (528/batch)
  //    QKx batch stride is S*2048 = 2*SD (interleaved layout!)
  gemm_bt<false, true, false><<<dim3(528, 1, Bb), 256, 0, stream>>>(
      QKx, QKx + 1024, Sb, 1024, 2048, 2048, S, 2 * SD, 2 * SD, SS, 1.0f);

  // 6. row softmax in place (also zero-pads rows to 128 boundary)
  softmax_rows<<<dim3(S, Bb), 256, 0, stream>>>(Sb, SS, S);

  // 7. out = P @ Vxt^T (causal k-limit; longest blocks first)
  gemm_bt<true, false, true><<<dim3(32, 8, Bb), 256, 0, stream>>>(
      Sb, Vxt, out, S, S, S, D, SS, SD, SD, 1.0f);
}